// Round 12
// baseline (297.641 us; speedup 1.0000x reference)
//
#include <hip/hip_runtime.h>
#include <math.h>

#define NSLOPE 0.2f
#define BIN_CH 8192
#define P2_CAP 5120
#define BKT_CAP 5120

typedef __attribute__((ext_vector_type(8)))  short bf16x8;
typedef __attribute__((ext_vector_type(4)))  float floatx4;
typedef __attribute__((ext_vector_type(16))) float floatx16;
typedef __attribute__((ext_vector_type(2)))  unsigned uswap2;

__device__ __forceinline__ unsigned short f2bf(float f) {
    unsigned u = __builtin_bit_cast(unsigned, f);
    u += 0x7fff + ((u >> 16) & 1);          // RNE
    return (unsigned short)(u >> 16);
}
__device__ __forceinline__ float bf2f(unsigned short h) {
    unsigned u = (unsigned)h << 16;
    return __builtin_bit_cast(float, u);
}

__device__ __forceinline__ void split8(const float* v, bf16x8& hi, bf16x8& lo) {
#pragma unroll
    for (int j = 0; j < 8; j++) {
        unsigned short h = f2bf(v[j]);
        hi[j] = (short)h;
        lo[j] = (short)f2bf(v[j] - bf2f(h));
    }
}

// HW packed f32x2 -> bf16x2 (RNE), low word = first operand
__device__ __forceinline__ unsigned cvtpk(float a, float b) {
    unsigned r;
    asm("v_cvt_pk_bf16_f32 %0, %1, %2" : "=v"(r) : "v"(a), "v"(b));
    return r;
}

__device__ __forceinline__ uswap2 pl32swap(unsigned a, unsigned b) {
    return __builtin_amdgcn_permlane32_swap(a, b, false, false);
}

__device__ __forceinline__ bf16x8 mk8(unsigned w0, unsigned w1, unsigned w2, unsigned w3) {
    union { unsigned u[4]; bf16x8 v; } t;
    t.u[0] = w0; t.u[1] = w1; t.u[2] = w2; t.u[3] = w3;
    return t.v;
}

// 16 post-epilogue floats of one transposed 32-col tile -> two bf16x8
// k-fragments for the next stage, via cvt_pk + permlane32_swap.
__device__ __forceinline__ void pack_swap(const float* v, bf16x8& f0, bf16x8& f1) {
    unsigned p00 = cvtpk(v[0],  v[1]);
    unsigned p01 = cvtpk(v[2],  v[3]);
    unsigned p10 = cvtpk(v[4],  v[5]);
    unsigned p11 = cvtpk(v[6],  v[7]);
    unsigned p20 = cvtpk(v[8],  v[9]);
    unsigned p21 = cvtpk(v[10], v[11]);
    unsigned p30 = cvtpk(v[12], v[13]);
    unsigned p31 = cvtpk(v[14], v[15]);
    uswap2 s00 = pl32swap(p00, p10);
    uswap2 s01 = pl32swap(p01, p11);
    uswap2 s10 = pl32swap(p20, p30);
    uswap2 s11 = pl32swap(p21, p31);
    f0 = mk8(s00[0], s01[0], s00[1], s01[1]);
    f1 = mk8(s10[0], s11[0], s10[1], s11[1]);
}

// ============================================================
// h-projection v2: TRANSPOSED dataflow (h^T = W^T x^T).
// ============================================================
__global__ __launch_bounds__(256, 2)
void hproj_kernel(const float* __restrict__ x,
                  const unsigned short* __restrict__ Whi,
                  const unsigned short* __restrict__ Wlo,
                  const float* __restrict__ asrc, const float* __restrict__ adst,
                  unsigned short* __restrict__ hb, float* __restrict__ alS,
                  float* __restrict__ alD, int M)
{
    const int lane = threadIdx.x & 63;
    const int wv   = threadIdx.x >> 6;
    const int l31  = lane & 31;
    const int half = lane >> 5;
    const int m0   = blockIdx.x * 128 + wv * 32;
    const int lane8 = lane * 8;

    int r0 = m0 + l31;
    const bool valid = (r0 < M);
    if (!valid) r0 = M - 1;

    const float* a0 = x + (size_t)r0 * 130 + 2 + half * 8;

    floatx16 acc[2];
    acc[0] = (floatx16)(0.f);
    acc[1] = (floatx16)(0.f);

#pragma unroll
    for (int kt = 0; kt < 8; kt++) {
        float av[8];
#pragma unroll
        for (int j = 0; j < 4; j++) {
            float2 q = *(const float2*)(a0 + kt * 16 + 2 * j);
            av[2 * j] = q.x; av[2 * j + 1] = q.y;
        }
        bf16x8 xh, xl;
        split8(av, xh, xl);
#pragma unroll
        for (int nt = 0; nt < 2; nt++) {
            const size_t w0 = (size_t)(nt * 8 + kt) * 512 + lane8;
            bf16x8 wh = *(const bf16x8*)(Whi + w0);
            bf16x8 wl = *(const bf16x8*)(Wlo + w0);
            acc[nt] = __builtin_amdgcn_mfma_f32_32x32x16_bf16(wh, xh, acc[nt], 0, 0, 0);
            acc[nt] = __builtin_amdgcn_mfma_f32_32x32x16_bf16(wl, xh, acc[nt], 0, 0, 0);
            acc[nt] = __builtin_amdgcn_mfma_f32_32x32x16_bf16(wh, xl, acc[nt], 0, 0, 0);
        }
    }

    float ps = 0.f, pd = 0.f;
    unsigned short* hp = hb + (size_t)r0 * 64;
#pragma unroll
    for (int nt = 0; nt < 2; nt++)
#pragma unroll
        for (int q = 0; q < 4; q++) {
            const int c0 = nt * 32 + q * 8 + 4 * half;
            float4 as4 = *(const float4*)(asrc + c0);
            float4 ad4 = *(const float4*)(adst + c0);
            float v0 = acc[nt][4*q+0], v1 = acc[nt][4*q+1];
            float v2 = acc[nt][4*q+2], v3 = acc[nt][4*q+3];
            ps += v0 * as4.x + v1 * as4.y + v2 * as4.z + v3 * as4.w;
            pd += v0 * ad4.x + v1 * ad4.y + v2 * ad4.z + v3 * ad4.w;
            if (valid) {
                uint2 pk;
                pk.x = cvtpk(v0, v1);
                pk.y = cvtpk(v2, v3);
                *(uint2*)(hp + c0) = pk;
            }
        }
    ps += __shfl_xor(ps, 32);
    pd += __shfl_xor(pd, 32);
    if (valid && half == 0) { alS[r0] = ps; alD[r0] = pd; }
}

// ============================================================
// Fused MLP v7: zero-LDS transposed dataflow + fragment-packed
// weights + full unroll (compile-time addresses -> deep hoisting).
// ============================================================
__global__ __launch_bounds__(128, 2)
void fused_mlp(const float* __restrict__ x3,
               const float* __restrict__ x,
               const unsigned short* __restrict__ f1Hi,
               const unsigned short* __restrict__ f2Hi,
               const unsigned short* __restrict__ f3Hi,
               const unsigned short* __restrict__ f3Lo,
               const float* __restrict__ cb, const float* __restrict__ u1,
               const float* __restrict__ u2, const float* __restrict__ fc2b,
               const float* __restrict__ fc3b,
               float* __restrict__ out, int M)
{
    const int lane = threadIdx.x & 63;
    const int wv   = threadIdx.x >> 6;
    const int l31  = lane & 31;
    const int half = lane >> 5;
    const int m0   = blockIdx.x * 64 + wv * 32;
    const int lane8 = lane * 8;

    // ---- x3 row fragments (B operand of transposed fc1), hi+lo ----
    bf16x8 ah[4], al[4];
    int r0 = m0 + l31; if (r0 >= M) r0 = M - 1;
    {
        const float* a0 = x3 + (size_t)r0 * 64 + half * 8;
#pragma unroll
        for (int kt = 0; kt < 4; kt++) {
            float av[8];
            float4 qa = *(const float4*)(a0 + kt * 16);
            float4 qb = *(const float4*)(a0 + kt * 16 + 4);
            av[0]=qa.x; av[1]=qa.y; av[2]=qa.z; av[3]=qa.w;
            av[4]=qb.x; av[5]=qb.y; av[6]=qb.z; av[7]=qb.w;
            split8(av, ah[kt], al[kt]);
        }
    }

    // rank-1 row scalars: one row per lane
    float2 xv = *(const float2*)(x + (size_t)r0 * 130);

    floatx16 acc2[4];
#pragma unroll
    for (int nt = 0; nt < 4; nt++) acc2[nt] = (floatx16)(0.f);

    // ---- fc1 (transposed) interleaved with fc2 K-accumulation ----
#pragma unroll
    for (int nt = 0; nt < 12; nt++) {
        const unsigned short* wp = f1Hi + (size_t)nt * 2048 + lane8;
        bf16x8 wh[4];
#pragma unroll
        for (int kt = 0; kt < 4; kt++) wh[kt] = *(const bf16x8*)(wp + kt * 512);
        const unsigned short* w2p = f2Hi + (size_t)nt * 1024 + lane8;
        bf16x8 w2[8];
#pragma unroll
        for (int nt2 = 0; nt2 < 4; nt2++) {
            w2[2 * nt2]     = *(const bf16x8*)(w2p + nt2 * 12288);
            w2[2 * nt2 + 1] = *(const bf16x8*)(w2p + nt2 * 12288 + 512);
        }

        floatx16 acc = (floatx16)(0.f);
#pragma unroll
        for (int kt = 0; kt < 4; kt++) {
            acc = __builtin_amdgcn_mfma_f32_32x32x16_bf16(wh[kt], ah[kt], acc, 0, 0, 0);
            acc = __builtin_amdgcn_mfma_f32_32x32x16_bf16(wh[kt], al[kt], acc, 0, 0, 0);
        }
        float v[16];
#pragma unroll
        for (int q = 0; q < 4; q++) {
            const int c0 = nt * 32 + q * 8 + 4 * half;
            float4 cb4 = *(const float4*)(cb + c0);
            float4 u14 = *(const float4*)(u1 + c0);
            float4 u24 = *(const float4*)(u2 + c0);
            float t0 = acc[4*q+0] + cb4.x + xv.x * u14.x + xv.y * u24.x;
            float t1 = acc[4*q+1] + cb4.y + xv.x * u14.y + xv.y * u24.y;
            float t2 = acc[4*q+2] + cb4.z + xv.x * u14.z + xv.y * u24.z;
            float t3 = acc[4*q+3] + cb4.w + xv.x * u14.w + xv.y * u24.w;
            v[4*q+0] = t0 > 0.f ? t0 : 0.f;
            v[4*q+1] = t1 > 0.f ? t1 : 0.f;
            v[4*q+2] = t2 > 0.f ? t2 : 0.f;
            v[4*q+3] = t3 > 0.f ? t3 : 0.f;
        }
        bf16x8 a2_0, a2_1;
        pack_swap(v, a2_0, a2_1);
#pragma unroll
        for (int nt2 = 0; nt2 < 4; nt2++) {
            acc2[nt2] = __builtin_amdgcn_mfma_f32_32x32x16_bf16(w2[2 * nt2],     a2_0, acc2[nt2], 0, 0, 0);
            acc2[nt2] = __builtin_amdgcn_mfma_f32_32x32x16_bf16(w2[2 * nt2 + 1], a2_1, acc2[nt2], 0, 0, 0);
        }
    }

    // ---- fc2 epilogue chunks feed fc3 K-accumulation (K=128) ----
    floatx16 acc3[2];
    acc3[0] = (floatx16)(0.f);
    acc3[1] = (floatx16)(0.f);
#pragma unroll
    for (int nt2 = 0; nt2 < 4; nt2++) {
        const unsigned short* w3p = f3Hi + (size_t)nt2 * 1024 + lane8;
        const unsigned short* w3q = f3Lo + (size_t)nt2 * 1024 + lane8;
        bf16x8 wh0 = *(const bf16x8*)(w3p);
        bf16x8 wl0 = *(const bf16x8*)(w3q);
        bf16x8 wh1 = *(const bf16x8*)(w3p + 512);
        bf16x8 wl1 = *(const bf16x8*)(w3q + 512);
        bf16x8 wh2 = *(const bf16x8*)(w3p + 4096);
        bf16x8 wl2 = *(const bf16x8*)(w3q + 4096);
        bf16x8 wh3 = *(const bf16x8*)(w3p + 4096 + 512);
        bf16x8 wl3 = *(const bf16x8*)(w3q + 4096 + 512);

        float v[16];
#pragma unroll
        for (int q = 0; q < 4; q++) {
            const int c0 = nt2 * 32 + q * 8 + 4 * half;
            float4 b4 = *(const float4*)(fc2b + c0);
            float t0 = acc2[nt2][4*q+0] + b4.x;
            float t1 = acc2[nt2][4*q+1] + b4.y;
            float t2 = acc2[nt2][4*q+2] + b4.z;
            float t3 = acc2[nt2][4*q+3] + b4.w;
            v[4*q+0] = t0 > 0.f ? t0 : 0.f;
            v[4*q+1] = t1 > 0.f ? t1 : 0.f;
            v[4*q+2] = t2 > 0.f ? t2 : 0.f;
            v[4*q+3] = t3 > 0.f ? t3 : 0.f;
        }
        bf16x8 a3_0, a3_1;
        pack_swap(v, a3_0, a3_1);
        acc3[0] = __builtin_amdgcn_mfma_f32_32x32x16_bf16(wh0, a3_0, acc3[0], 0, 0, 0);
        acc3[0] = __builtin_amdgcn_mfma_f32_32x32x16_bf16(wl0, a3_0, acc3[0], 0, 0, 0);
        acc3[0] = __builtin_amdgcn_mfma_f32_32x32x16_bf16(wh1, a3_1, acc3[0], 0, 0, 0);
        acc3[0] = __builtin_amdgcn_mfma_f32_32x32x16_bf16(wl1, a3_1, acc3[0], 0, 0, 0);
        acc3[1] = __builtin_amdgcn_mfma_f32_32x32x16_bf16(wh2, a3_0, acc3[1], 0, 0, 0);
        acc3[1] = __builtin_amdgcn_mfma_f32_32x32x16_bf16(wl2, a3_0, acc3[1], 0, 0, 0);
        acc3[1] = __builtin_amdgcn_mfma_f32_32x32x16_bf16(wh3, a3_1, acc3[1], 0, 0, 0);
        acc3[1] = __builtin_amdgcn_mfma_f32_32x32x16_bf16(wl3, a3_1, acc3[1], 0, 0, 0);
    }

    // ---- store: lane owns row l31; 16B chunks per reg-quad ----
    int row = m0 + l31;
    if (row < M) {
        float* op = out + (size_t)row * 64;
#pragma unroll
        for (int nt3 = 0; nt3 < 2; nt3++)
#pragma unroll
            for (int q = 0; q < 4; q++) {
                const int c0 = nt3 * 32 + q * 8 + 4 * half;
                float4 b4 = *(const float4*)(fc3b + c0);
                float4 o;
                o.x = acc3[nt3][4*q+0] + b4.x;
                o.y = acc3[nt3][4*q+1] + b4.y;
                o.z = acc3[nt3][4*q+2] + b4.z;
                o.w = acc3[nt3][4*q+3] + b4.w;
                *(float4*)(op + c0) = o;
            }
    }
}

// ============================================================
// Merged prep: pack all four weight planes + rank-1 folds + gcur.
// ============================================================
__global__ __launch_bounds__(256)
void prep_all(const float* __restrict__ gat_w, const float* __restrict__ fc1w,
              const float* __restrict__ fc2w, const float* __restrict__ fc3w,
              const float* __restrict__ w1, const float* __restrict__ b1,
              const float* __restrict__ w2, const float* __restrict__ b2,
              const float* __restrict__ fc1b,
              unsigned short* __restrict__ gatHi, unsigned short* __restrict__ gatLo,
              unsigned short* __restrict__ f1Hi, unsigned short* __restrict__ f1Lo,
              unsigned short* __restrict__ f2Hi, unsigned short* __restrict__ f2Lo,
              unsigned short* __restrict__ f3Hi, unsigned short* __restrict__ f3Lo,
              float* __restrict__ u1, float* __restrict__ u2, float* __restrict__ cb,
              int* __restrict__ gcur)
{
    int g = blockIdx.x * 256 + threadIdx.x;
    if (g < 90112) {
        const float* W; unsigned short *hi, *lo;
        int idx, K, ldw;
        if (g < 8192)       { idx = g;         W = gat_w;            hi = gatHi; lo = gatLo; K = 128; ldw = 64;  }
        else if (g < 32768) { idx = g - 8192;  W = fc1w + 128 * 384; hi = f1Hi;  lo = f1Lo;  K = 64;  ldw = 384; }
        else if (g < 81920) { idx = g - 32768; W = fc2w;             hi = f2Hi;  lo = f2Lo;  K = 384; ldw = 128; }
        else                { idx = g - 81920; W = fc3w;             hi = f3Hi;  lo = f3Lo;  K = 128; ldw = 64;  }
        int n = idx / K, k = idx - n * K;
        float v = W[(size_t)k * ldw + n];
        unsigned short h = f2bf(v);
        unsigned short l = f2bf(v - bf2f(h));
        int lane = ((k >> 3) & 1) * 32 + (n & 31);
        int tile = (n >> 5) * (K >> 4) + (k >> 4);
        size_t pos = ((size_t)tile * 64 + lane) * 8 + (k & 7);
        hi[pos] = h;
        lo[pos] = l;
    } else if (g < 90496) {
        int j = g - 90112;           // 0..383
        float s1 = 0.f, s2 = 0.f, c = fc1b[j];
        for (int k = 0; k < 64; k++) {
            float wv = fc1w[k * 384 + j];
            s1 += w1[k] * wv; c += b1[k] * wv;
        }
        for (int k = 0; k < 64; k++) {
            float wv = fc1w[(64 + k) * 384 + j];
            s2 += w2[k] * wv; c += b2[k] * wv;
        }
        u1[j] = s1; u2[j] = s2; cb[j] = c;
    } else if (g < 91008) {
        int b = g - 90496;           // 0..511
        gcur[b] = b * BKT_CAP;
    }
}

// ============================================================
// Scatter pass 1: BIN edges into 256-node buckets with LDS reorder.
// ============================================================
__global__ __launch_bounds__(256)
void bin_kernel(const int* __restrict__ ei, int E, int total,
                int* __restrict__ gcur, unsigned* __restrict__ items)
{
    __shared__ unsigned       stage[BIN_CH];   // 32 KB
    __shared__ unsigned short bidx[BIN_CH];    // 16 KB
    __shared__ int hist[512], lofs[512], base[512], cnt2[512]; // 8 KB
    __shared__ int pairs[256];                 // 1 KB

    const int t     = threadIdx.x;
    const int base0 = blockIdx.x * BIN_CH;
    const int cnt   = min(BIN_CH, total - base0);

    for (int b = t; b < 512; b += 256) { hist[b] = 0; cnt2[b] = 0; }
    __syncthreads();

    // 1. histogram over buckets
    for (int i = t; i < cnt; i += 256) {
        int tt = base0 + i;
        int d = (tt < E) ? ei[E + tt] : (tt - E);
        atomicAdd(&hist[d >> 8], 1);
    }
    __syncthreads();

    // 2. exclusive scan of 512 hist entries (pair trick) + region bases
    int h0 = hist[2 * t], h1 = hist[2 * t + 1];
    pairs[t] = h0 + h1;
    __syncthreads();
    for (int off = 1; off < 256; off <<= 1) {
        int x = (t >= off) ? pairs[t - off] : 0;
        __syncthreads();
        pairs[t] += x;
        __syncthreads();
    }
    int excl = (t > 0) ? pairs[t - 1] : 0;
    lofs[2 * t]     = excl;
    lofs[2 * t + 1] = excl + h0;
    for (int b = t; b < 512; b += 256)
        if (hist[b] > 0) base[b] = atomicAdd(&gcur[b], hist[b]);
    __syncthreads();

    // 3. rank + stage into LDS sorted by bucket
    for (int i = t; i < cnt; i += 256) {
        int tt = base0 + i;
        int d, s;
        if (tt < E) { d = ei[E + tt]; s = ei[tt]; }
        else        { d = tt - E;     s = d;      }
        int b = d >> 8;
        int r = atomicAdd(&cnt2[b], 1);
        int p = lofs[b] + r;
        stage[p] = ((unsigned)s << 8) | (unsigned)(d & 255);
        bidx[p]  = (unsigned short)b;
    }
    __syncthreads();

    // 4. coalesced flush: consecutive lanes -> consecutive addresses
    for (int j = t; j < cnt; j += 256) {
        int b = bidx[j];
        items[base[b] + (j - lofs[b])] = stage[j];
    }
}

// ============================================================
// Scatter pass 2: per-bucket CSR placement + per-node rowptr build.
// Each block rebuilds the 512-bucket prefix (from post-bin gcur).
// ============================================================
__global__ __launch_bounds__(256)
void bucket_scatter(const unsigned* __restrict__ items,
                    const int* __restrict__ gcur,
                    int* __restrict__ rowptr,
                    const float* __restrict__ alS, const float* __restrict__ alD,
                    uint2* __restrict__ sev, int N, int total)
{
    __shared__ int   lhist[256];
    __shared__ int   sh[256];
    __shared__ int   lcur[256];
    __shared__ int   lofs[512];
    __shared__ uint2 buf[P2_CAP];              // 40 KB

    const int b  = blockIdx.x;
    const int t  = threadIdx.x;
    const int n0 = b << 8;
    const size_t ib = (size_t)b * BKT_CAP;

    // bucket prefix: counts from post-bin cursors
    {
        int g0 = gcur[2 * t]     - (2 * t) * BKT_CAP;
        int g1 = gcur[2 * t + 1] - (2 * t + 1) * BKT_CAP;
        sh[t] = g0 + g1;
        __syncthreads();
        for (int off = 1; off < 256; off <<= 1) {
            int x = (t >= off) ? sh[t - off] : 0;
            __syncthreads();
            sh[t] += x;
            __syncthreads();
        }
        int excl = (t > 0) ? sh[t - 1] : 0;
        lofs[2 * t]     = excl;
        lofs[2 * t + 1] = excl + g0;
        __syncthreads();
    }
    const int i0  = lofs[b];
    const int cnt = gcur[b] - b * BKT_CAP;

    lhist[t] = 0;
    __syncthreads();
    // per-node histogram of this bucket
    for (int j = t; j < cnt; j += 256)
        atomicAdd(&lhist[items[ib + j] & 255u], 1);
    __syncthreads();
    // exclusive scan over 256 local nodes
    sh[t] = lhist[t];
    __syncthreads();
    for (int off = 1; off < 256; off <<= 1) {
        int x = (t >= off) ? sh[t - off] : 0;
        __syncthreads();
        sh[t] += x;
        __syncthreads();
    }
    int excl = (t > 0) ? sh[t - 1] : 0;
    if (n0 + t < N) rowptr[n0 + t] = i0 + excl;
    lcur[t] = excl;
    __syncthreads();

    const bool direct = (cnt > P2_CAP);        // statistical never; correctness net
    for (int j = t; j < cnt; j += 256) {
        unsigned raw = items[ib + j];
        int dl = (int)(raw & 255u);
        int s  = (int)(raw >> 8);
        float v = alS[s] + alD[n0 + dl];
        v = v > 0.f ? v : NSLOPE * v;
        float ex = expf(v);
        int r = atomicAdd(&lcur[dl], 1);
        uint2 it = make_uint2((unsigned)s, __builtin_bit_cast(unsigned, ex));
        if (direct) sev[i0 + r] = it;
        else        buf[r] = it;
    }
    __syncthreads();
    if (!direct)
        for (int j = t; j < cnt; j += 256) sev[i0 + j] = buf[j];
}

// ============================================================
// Gather-aggregate: HALF-WAVE (32 lanes) per node.
// ============================================================
__global__ __launch_bounds__(256)
void aggregate_kernel(const int* __restrict__ rowptr,
                      const uint2* __restrict__ sev,
                      const unsigned int* __restrict__ hb32,   // h as [N][32] u32
                      const float* __restrict__ gatb,
                      float* __restrict__ x3, int N, int total)
{
    int node = blockIdx.x * 8 + (threadIdx.x >> 5);
    int l    = threadIdx.x & 31;
    int hsel = threadIdx.x & 32;              // 0 or 32: shfl source base
    if (node >= N) return;
    int start = rowptr[node];
    int end   = (node + 1 < N) ? rowptr[node + 1] : total;
    float ax = 0.f, ay = 0.f, den = 0.f;
    for (int p = start; p < end; p += 32) {
        int idx = p + l;
        uint2 se = (idx < end) ? sev[idx] : make_uint2(0u, 0u);
        int si = (int)se.x;
        float ex = __builtin_bit_cast(float, se.y);
        int cnt = end - p; if (cnt > 32) cnt = 32;
        int j = 0;
        for (; j + 4 <= cnt; j += 4) {
            int   s0 = __shfl(si, hsel | j),       s1 = __shfl(si, hsel | (j + 1));
            int   s2 = __shfl(si, hsel | (j + 2)), s3 = __shfl(si, hsel | (j + 3));
            float e0 = __shfl(ex, hsel | j),       e1 = __shfl(ex, hsel | (j + 1));
            float e2 = __shfl(ex, hsel | (j + 2)), e3 = __shfl(ex, hsel | (j + 3));
            unsigned w0 = hb32[(size_t)s0 * 32 + l];
            unsigned w1 = hb32[(size_t)s1 * 32 + l];
            unsigned w2 = hb32[(size_t)s2 * 32 + l];
            unsigned w3 = hb32[(size_t)s3 * 32 + l];
            den += (e0 + e1) + (e2 + e3);
            ax += e0 * bf2f((unsigned short)(w0 & 0xFFFFu));
            ay += e0 * bf2f((unsigned short)(w0 >> 16));
            ax += e1 * bf2f((unsigned short)(w1 & 0xFFFFu));
            ay += e1 * bf2f((unsigned short)(w1 >> 16));
            ax += e2 * bf2f((unsigned short)(w2 & 0xFFFFu));
            ay += e2 * bf2f((unsigned short)(w2 >> 16));
            ax += e3 * bf2f((unsigned short)(w3 & 0xFFFFu));
            ay += e3 * bf2f((unsigned short)(w3 >> 16));
        }
        for (; j < cnt; j++) {
            int   sj = __shfl(si, hsel | j);
            float ej = __shfl(ex, hsel | j);
            unsigned w = hb32[(size_t)sj * 32 + l];
            den += ej;
            ax += ej * bf2f((unsigned short)(w & 0xFFFFu));
            ay += ej * bf2f((unsigned short)(w >> 16));
        }
    }
    float inv = 1.f / (den + 1e-16f);
    float2 o;
    o.x = ax * inv + gatb[2 * l];
    o.y = ay * inv + gatb[2 * l + 1];
    *(float2*)&x3[(size_t)node * 64 + 2 * l] = o;
}

extern "C" void kernel_launch(void* const* d_in, const int* in_sizes, int n_in,
                              void* d_out, int out_size, void* d_ws, size_t ws_size,
                              hipStream_t stream)
{
    const float* x      = (const float*)d_in[0];
    const int*   ei     = (const int*)d_in[1];
    const float* w1     = (const float*)d_in[2];
    const float* b1     = (const float*)d_in[3];
    const float* w2     = (const float*)d_in[4];
    const float* b2     = (const float*)d_in[5];
    const float* gat_w  = (const float*)d_in[6];
    const float* gat_as = (const float*)d_in[7];
    const float* gat_ad = (const float*)d_in[8];
    const float* gat_b  = (const float*)d_in[9];
    const float* fc1w   = (const float*)d_in[10];
    const float* fc1b   = (const float*)d_in[11];
    const float* fc2w   = (const float*)d_in[12];
    const float* fc2b   = (const float*)d_in[13];
    const float* fc3w   = (const float*)d_in[14];
    const float* fc3b   = (const float*)d_in[15];

    const int N = in_sizes[0] / 130;
    const int E = in_sizes[1] / 2;
    const int total = E + N;
    float* out = (float*)d_out;

    // ---- workspace layout: EVERY array 4KB-aligned (pins L2-set
    // mapping of the hot weight planes against layout edits) ----
    float* ws = (float*)d_ws;
    size_t off = 0;
    auto a4k = [](size_t o) { return (o + 1023) & ~(size_t)1023; };  // in floats
    unsigned short* hb = (unsigned short*)(ws + off); off = a4k(off + (size_t)N * 32);
    float* x3     = ws + off; off = a4k(off + (size_t)N * 64);
    float* alS    = ws + off; off = a4k(off + (size_t)N);
    float* alD    = ws + off; off = a4k(off + (size_t)N);
    float* u1     = ws + off; off = a4k(off + 512);
    float* u2     = ws + off; off = a4k(off + 512);
    float* cb     = ws + off; off = a4k(off + 512);
    int*   rowptr = (int*)(ws + off); off = a4k(off + (size_t)N);
    int*   gcur   = (int*)(ws + off); off = a4k(off + 512);
    uint2* sev    = (uint2*)(ws + off); off = a4k(off + (size_t)total * 2);
    unsigned* items = (unsigned*)(ws + off); off = a4k(off + (size_t)512 * BKT_CAP);
    unsigned short* gatHi = (unsigned short*)(ws + off); off = a4k(off + 4096);
    unsigned short* gatLo = (unsigned short*)(ws + off); off = a4k(off + 4096);
    unsigned short* f1Hi  = (unsigned short*)(ws + off); off = a4k(off + 12288);
    unsigned short* f1Lo  = (unsigned short*)(ws + off); off = a4k(off + 12288);
    unsigned short* f2Hi  = (unsigned short*)(ws + off); off = a4k(off + 24576);
    unsigned short* f2Lo  = (unsigned short*)(ws + off); off = a4k(off + 24576);
    unsigned short* f3Hi  = (unsigned short*)(ws + off); off = a4k(off + 4096);
    unsigned short* f3Lo  = (unsigned short*)(ws + off); off = a4k(off + 4096);

    // merged prep: pack planes + rank-1 folds + gcur seeding
    prep_all<<<(91008 + 255) / 256, 256, 0, stream>>>(gat_w, fc1w, fc2w, fc3w,
                                                      w1, b1, w2, b2, fc1b,
                                                      gatHi, gatLo, f1Hi, f1Lo,
                                                      f2Hi, f2Lo, f3Hi, f3Lo,
                                                      u1, u2, cb, gcur);

    // h = x[:,2:] @ gat_w (bf16 out) + alpha fold — transposed v2
    hproj_kernel<<<(N + 127) / 128, 256, 0, stream>>>(x, gatHi, gatLo,
                                                      gat_as, gat_ad, hb, alS, alD, N);

    // binned scatter into fixed bucket regions (no count pre-pass)
    int nbin = (total + BIN_CH - 1) / BIN_CH;
    bin_kernel<<<nbin, 256, 0, stream>>>(ei, E, total, gcur, items);
    int nbkt = (N + 255) / 256;
    bucket_scatter<<<nbkt, 256, 0, stream>>>(items, gcur, rowptr,
                                             alS, alD, sev, N, total);

    aggregate_kernel<<<(N + 7) / 8, 256, 0, stream>>>(rowptr, sev,
                                                      (const unsigned int*)hb,
                                                      gat_b, x3, N, total);

    // fused MLP v7: full-unroll deep-prefetch, zero-LDS
    fused_mlp<<<(N + 63) / 64, 128, 0, stream>>>(x3, x,
                                                 f1Hi, f2Hi, f3Hi, f3Lo,
                                                 cb, u1, u2, fc2b, fc3b, out, N);
}